// Round 12
// baseline (755.369 us; speedup 1.0000x reference)
//
#include <hip/hip_runtime.h>
#include <math.h>

// Problem constants (fixed by setup_inputs)
#define B   16
#define L   512
#define H   768
#define HV4 192      // H/4 float4s per row
#define S1  32
#define S2  128
#define NS  8
#define M   4
#define CH  16       // L-chunk rows per partial block
#define NCHUNK 32    // L / CH
#define REP 8        // MEASUREMENT ROUND: x8 self-replication, output-preserving

// ---------------------------------------------------------------------------
// K1: R11 k_pool with the gather loops run REP times (accumulate, scale 1/REP).
// ---------------------------------------------------------------------------
__global__ __launch_bounds__(384)
void k_pool(const float* __restrict__ e1, const float* __restrict__ e2,
            const int* __restrict__ am,
            const float* __restrict__ s1, const float* __restrict__ s2,
            const int* __restrict__ iam,
            const float* __restrict__ hs, const int* __restrict__ st_,
            const int* __restrict__ en_,
            float* __restrict__ row_cls,
            float* __restrict__ sp_part, float* __restrict__ sp_cnt,
            float* __restrict__ sel_part, float* __restrict__ sel_cnt) {
  const int bid = blockIdx.x;
  const int t = threadIdx.x;
  const int half = t / 192;
  const int tt = t % 192;
  __shared__ int   idxL[S2];
  __shared__ int   cntS;
  __shared__ float4 pf[192];

  if (bid < 512) {
    const int i = bid;
    if (t < 64) {
      const int m0 = am[i * S2 + t];
      const int m1 = am[i * S2 + 64 + t];
      const unsigned long long b0 = __ballot(m0 != 0);
      const unsigned long long b1 = __ballot(m1 != 0);
      const int c0 = (int)__popcll(b0);
      if (m0) idxL[(int)__popcll(b0 & ((1ULL << t) - 1))] = t;
      if (m1) idxL[c0 + (int)__popcll(b1 & ((1ULL << t) - 1))] = 64 + t;
      if (t == 0) cntS = c0 + (int)__popcll(b1);
    }
    __syncthreads();
    const int cnt = cntS;
    const int cntH = (cnt + 1 - half) >> 1;
    const float4* p1 = (const float4*)e1 + (size_t)i * (S2 * HV4) + tt;
    const float4* p2 = (const float4*)e2 + (size_t)i * (S2 * HV4) + tt;
    float ax = 0.f, ay = 0.f, az = 0.f, aw = 0.f;
    #pragma unroll 1
    for (int rep = 0; rep < REP; ++rep) {
      asm volatile("" ::: "memory");
      int kk = 0;
      for (; kk + 3 < cntH; kk += 4) {
        const int j0 = idxL[2 * kk + half];
        const int j1 = idxL[2 * (kk + 1) + half];
        const int j2 = idxL[2 * (kk + 2) + half];
        const int j3 = idxL[2 * (kk + 3) + half];
        float4 a0 = p1[j0 * HV4], b0 = p2[j0 * HV4];
        float4 a1 = p1[j1 * HV4], b1 = p2[j1 * HV4];
        float4 a2 = p1[j2 * HV4], b2 = p2[j2 * HV4];
        float4 a3 = p1[j3 * HV4], b3 = p2[j3 * HV4];
        ax += (a0.x + b0.x) + (a1.x + b1.x) + (a2.x + b2.x) + (a3.x + b3.x);
        ay += (a0.y + b0.y) + (a1.y + b1.y) + (a2.y + b2.y) + (a3.y + b3.y);
        az += (a0.z + b0.z) + (a1.z + b1.z) + (a2.z + b2.z) + (a3.z + b3.z);
        aw += (a0.w + b0.w) + (a1.w + b1.w) + (a2.w + b2.w) + (a3.w + b3.w);
      }
      for (; kk < cntH; ++kk) {
        const int j = idxL[2 * kk + half];
        float4 a = p1[j * HV4], b = p2[j * HV4];
        ax += a.x + b.x; ay += a.y + b.y; az += a.z + b.z; aw += a.w + b.w;
      }
    }
    if (half == 1) { float4 o; o.x = ax; o.y = ay; o.z = az; o.w = aw; pf[tt] = o; }
    __syncthreads();
    if (half == 0) {
      const float inv = 1.f / ((float)REP * (float)cnt);
      float4 o = pf[tt];
      o.x = (ax + o.x) * inv; o.y = (ay + o.y) * inv;
      o.z = (az + o.z) * inv; o.w = (aw + o.w) * inv;
      ((float4*)row_cls)[(size_t)i * HV4 + tt] = o;
    }
  } else if (bid < 1024) {
    const int blk = bid - 512;
    const int b = blk >> 5, c = blk & 31;
    if (t < 64) {
      const int m = (t < CH) ? iam[b * L + c * CH + t] : 0;
      const unsigned long long bm = __ballot(m != 0);
      if (m) idxL[(int)__popcll(bm & ((1ULL << t) - 1))] = t;
      if (t == 0) { const int cc = (int)__popcll(bm); cntS = cc; sp_cnt[blk] = (float)cc; }
    }
    __syncthreads();
    const int cnt = cntS;
    const int cntH = (cnt + 1 - half) >> 1;
    const float4* p1 = (const float4*)s1 + ((size_t)b * L + c * CH) * HV4 + tt;
    const float4* p2 = (const float4*)s2 + ((size_t)b * L + c * CH) * HV4 + tt;
    float ax = 0.f, ay = 0.f, az = 0.f, aw = 0.f;
    #pragma unroll 1
    for (int rep = 0; rep < REP; ++rep) {
      asm volatile("" ::: "memory");
      int kk = 0;
      for (; kk + 1 < cntH; kk += 2) {
        const int l0 = idxL[2 * kk + half];
        const int l1 = idxL[2 * (kk + 1) + half];
        float4 a0 = p1[l0 * HV4], b0 = p2[l0 * HV4];
        float4 a1 = p1[l1 * HV4], b1 = p2[l1 * HV4];
        ax += (a0.x + b0.x) + (a1.x + b1.x);
        ay += (a0.y + b0.y) + (a1.y + b1.y);
        az += (a0.z + b0.z) + (a1.z + b1.z);
        aw += (a0.w + b0.w) + (a1.w + b1.w);
      }
      for (; kk < cntH; ++kk) {
        const int l = idxL[2 * kk + half];
        float4 a = p1[l * HV4], b = p2[l * HV4];
        ax += a.x + b.x; ay += a.y + b.y; az += a.z + b.z; aw += a.w + b.w;
      }
    }
    if (half == 1) { float4 o; o.x = ax; o.y = ay; o.z = az; o.w = aw; pf[tt] = o; }
    __syncthreads();
    if (half == 0) {
      const float invr = 1.f / (float)REP;
      float4 o = pf[tt];
      o.x = (o.x + ax) * invr; o.y = (o.y + ay) * invr;
      o.z = (o.z + az) * invr; o.w = (o.w + aw) * invr;
      ((float4*)sp_part)[(size_t)blk * HV4 + tt] = o;
    }
  } else {
    const int blk = bid - 1024;
    const int b = blk >> 5, c = blk & 31;
    const int st = st_[b], en = en_[b];
    const int lo = st > c * CH ? st : c * CH;
    const int hi = en < c * CH + CH ? en : c * CH + CH;
    const float4* p = (const float4*)hs + (size_t)b * L * HV4 + tt;
    float ax = 0.f, ay = 0.f, az = 0.f, aw = 0.f;
    #pragma unroll 1
    for (int rep = 0; rep < REP; ++rep) {
      asm volatile("" ::: "memory");
      for (int l = lo + half; l < hi; l += 2) {
        float4 a0 = p[l * HV4];
        ax += a0.x; ay += a0.y; az += a0.z; aw += a0.w;
      }
    }
    if (half == 1) { float4 o; o.x = ax; o.y = ay; o.z = az; o.w = aw; pf[tt] = o; }
    __syncthreads();
    if (half == 0) {
      const float invr = 1.f / (float)REP;
      float4 o = pf[tt];
      o.x = (o.x + ax) * invr; o.y = (o.y + ay) * invr;
      o.z = (o.z + az) * invr; o.w = (o.w + aw) * invr;
      ((float4*)sel_part)[(size_t)blk * HV4 + tt] = o;
      if (tt == 0) sel_cnt[blk] = (float)(hi > lo ? hi - lo : 0);
    }
  }
}

// ---------------------------------------------------------------------------
// K2: R11 k_sp, whole body x REP (idempotent).
// ---------------------------------------------------------------------------
__global__ __launch_bounds__(256)
void k_sp(const float* __restrict__ sp_part, const float* __restrict__ sp_cnt,
          const float* __restrict__ sel_part, const float* __restrict__ sel_cnt,
          const float* __restrict__ gamma_s, const float* __restrict__ beta_s,
          float* __restrict__ sp, float* __restrict__ sel_ln) {
  const int bid = blockIdx.x, t = threadIdx.x;
  const int lane = t & 63, w = t >> 6;
  __shared__ float red[8];
  #pragma unroll 1
  for (int rep = 0; rep < REP; ++rep) {
    asm volatile("" ::: "memory");
    if (bid < B) {
      const int b = bid;
      float csp = 0.f;
      for (int c = 0; c < NCHUNK; ++c) csp += sp_cnt[b * NCHUNK + c];
      const float inv = 1.f / csp;
      #pragma unroll
      for (int k = 0; k < 3; ++k) {
        const int h = t + k * 256;
        float a = 0.f;
        #pragma unroll
        for (int c = 0; c < NCHUNK; ++c)
          a += sp_part[((size_t)b * NCHUNK + c) * H + h];
        sp[(size_t)b * H + h] = a * inv;
      }
    } else {
      const int b = bid - B;
      float csel = 0.f;
      for (int c = 0; c < NCHUNK; ++c) csel += sel_cnt[b * NCHUNK + c];
      const float invc = 1.f / csel;
      float selv[3];
      #pragma unroll
      for (int k = 0; k < 3; ++k) {
        const int h = t + k * 256;
        float s = 0.f;
        #pragma unroll
        for (int c = 0; c < NCHUNK; ++c)
          s += sel_part[((size_t)b * NCHUNK + c) * H + h];
        selv[k] = s * invc;
      }
      float s = selv[0] + selv[1] + selv[2];
      float ss = selv[0] * selv[0] + selv[1] * selv[1] + selv[2] * selv[2];
      #pragma unroll
      for (int off = 32; off > 0; off >>= 1) {
        s += __shfl_down(s, off);
        ss += __shfl_down(ss, off);
      }
      if (lane == 0) { red[w] = s; red[4 + w] = ss; }
      __syncthreads();
      const float S = red[0] + red[1] + red[2] + red[3];
      const float SS = red[4] + red[5] + red[6] + red[7];
      const float mu = S / (float)H;
      const float var = SS / (float)H - mu * mu;
      const float rstd = rsqrtf(var + 1e-12f);
      #pragma unroll
      for (int k = 0; k < 3; ++k) {
        const int h = t + k * 256;
        sel_ln[(size_t)b * H + h] = (selv[k] - mu) * rstd * gamma_s[h] + beta_s[h];
      }
    }
    __syncthreads();
  }
}

// ---------------------------------------------------------------------------
// K3: R11 k_mid_q, whole body x REP (idempotent).
// ---------------------------------------------------------------------------
__global__ __launch_bounds__(1024)
void k_mid_q(const float* __restrict__ sp, const float* __restrict__ W_attn,
             const float* __restrict__ rc, float* __restrict__ simp) {
  const int bid = blockIdx.x, t = threadIdx.x;
  const int b = bid / 12, ht = bid % 12;
  const int lane = t & 63, w = t >> 6;
  __shared__ float spL[H];
  __shared__ float red[1024];
  __shared__ float qt[64];
  #pragma unroll 1
  for (int rep = 0; rep < REP; ++rep) {
    asm volatile("" ::: "memory");
    if (t < H) spL[t] = sp[(size_t)b * H + t];
    __syncthreads();
    {
      const int h = ht * 64 + lane;
      const float* wp = W_attn + (size_t)(w * 48) * H + h;
      const float* sv = spL + w * 48;
      float acc = 0.f;
      #pragma unroll 8
      for (int i = 0; i < 48; ++i) acc += sv[i] * wp[(size_t)i * H];
      red[t] = acc;
    }
    __syncthreads();
    if (t < 64) {
      float a = 0.f;
      #pragma unroll
      for (int ww = 0; ww < 16; ++ww) a += red[ww * 64 + t];
      qt[t] = a;
    }
    __syncthreads();
    {
      const int i = t >> 5, sub = t & 31;
      const float* rr = rc + (size_t)(b * S1 + i) * H + ht * 64 + sub * 2;
      float p = qt[sub * 2] * rr[0] + qt[sub * 2 + 1] * rr[1];
      p += __shfl_down(p, 16);
      p += __shfl_down(p, 8);
      p += __shfl_down(p, 4);
      p += __shfl_down(p, 2);
      p += __shfl_down(p, 1);
      if (sub == 0) simp[((size_t)b * 12 + ht) * S1 + i] = p;
    }
    __syncthreads();
  }
}

// ---------------------------------------------------------------------------
// K4: R11 k_attn_tr, whole body x REP (idempotent).
// ---------------------------------------------------------------------------
__global__ __launch_bounds__(1024)
void k_attn_tr(const float* __restrict__ simp, const float* __restrict__ rc,
               const int* __restrict__ extra_index,
               const float* __restrict__ W_t, const float* __restrict__ b_t,
               float* __restrict__ yb) {
  const int bid = blockIdx.x, t = threadIdx.x;
  const int b = bid / 12, hc = bid % 12;
  const int lane = t & 63, w = t >> 6;
  __shared__ float pL[NS * H];
  __shared__ float red[1024];
  __shared__ float simR[S1];
  __shared__ float w2L[S1];
  #pragma unroll 1
  for (int rep = 0; rep < REP; ++rep) {
    asm volatile("" ::: "memory");
    if (t < S1) {
      float a = 0.f;
      for (int ht = 0; ht < 12; ++ht)
        a += simp[((size_t)b * 12 + ht) * S1 + t];
      simR[t] = a;
    }
    __syncthreads();
    if (t < NS) {
      const int vid = extra_index[b * NS + t];
      const float scale = 0.036084391824351615f;  // 1/sqrt(768)
      float x[M], mx = -1e30f;
      #pragma unroll
      for (int m = 0; m < M; ++m) {
        x[m] = (m < vid) ? simR[t * M + m] * scale : -1e30f;
        mx = fmaxf(mx, x[m]);
      }
      float s = 0.f, e[M];
      #pragma unroll
      for (int m = 0; m < M; ++m) { e[m] = expf(x[m] - mx); s += e[m]; }
      #pragma unroll
      for (int m = 0; m < M; ++m) w2L[t * M + m] = e[m] / s;
    }
    __syncthreads();
    if (t < H) {
      const int d = t;
      #pragma unroll
      for (int n = 0; n < NS; ++n) {
        float p = 0.f;
        #pragma unroll
        for (int m = 0; m < M; ++m)
          p += w2L[n * M + m] * rc[(size_t)(b * S1 + n * M + m) * H + d];
        pL[n * H + d] = p;
      }
    }
    __syncthreads();
    {
      const int n = w & 7, dh = w >> 3;
      const int h = hc * 64 + lane;
      const float4* wr = (const float4*)(W_t + (size_t)h * H) + dh * 96;
      const float4* pq = (const float4*)(pL + n * H) + dh * 96;
      float acc = 0.f;
      #pragma unroll 8
      for (int d = 0; d < 96; ++d) {
        const float4 wv = wr[d];
        const float4 pv = pq[d];
        acc += wv.x * pv.x + wv.y * pv.y + wv.z * pv.z + wv.w * pv.w;
      }
      red[t] = acc;
    }
    __syncthreads();
    if (w < 8) {
      const int n = w;
      const int h = hc * 64 + lane;
      yb[((size_t)b * NS + n) * H + h] = red[t] + red[t + 512] + b_t[h];
    }
    __syncthreads();
  }
}

// ---------------------------------------------------------------------------
// K5: R7 k_lnscore, whole body x REP (idempotent).
// ---------------------------------------------------------------------------
__global__ __launch_bounds__(256)
void k_lnscore(const float* __restrict__ yb, const float* __restrict__ gamma,
               const float* __restrict__ beta, const float* __restrict__ sel_ln,
               float* __restrict__ out) {
  const int b = blockIdx.x, t = threadIdx.x;
  const int lane = t & 63, w = t >> 6;
  __shared__ float redS[NS * 4];
  __shared__ float redQ[NS * 4];
  #pragma unroll 1
  for (int rep = 0; rep < REP; ++rep) {
    asm volatile("" ::: "memory");
    float v[NS][3];
    for (int n = 0; n < NS; ++n) {
      float s = 0.f, ss = 0.f;
      #pragma unroll
      for (int k = 0; k < 3; ++k) {
        const float x = yb[((size_t)b * NS + n) * H + t + k * 256];
        v[n][k] = x; s += x; ss += x * x;
      }
      #pragma unroll
      for (int off = 32; off > 0; off >>= 1) {
        s += __shfl_down(s, off);
        ss += __shfl_down(ss, off);
      }
      if (lane == 0) { redS[n * 4 + w] = s; redQ[n * 4 + w] = ss; }
    }
    __syncthreads();
    float g[3], be[3];
    #pragma unroll
    for (int k = 0; k < 3; ++k) { g[k] = gamma[t + k * 256]; be[k] = beta[t + k * 256]; }
    float S[3] = {0.f, 0.f, 0.f}, SS[3] = {0.f, 0.f, 0.f};
    for (int n = 0; n < NS; ++n) {
      const float Sn = redS[n * 4] + redS[n * 4 + 1] + redS[n * 4 + 2] + redS[n * 4 + 3];
      const float Qn = redQ[n * 4] + redQ[n * 4 + 1] + redQ[n * 4 + 2] + redQ[n * 4 + 3];
      const float mu = Sn / (float)H;
      const float var = Qn / (float)H - mu * mu;
      const float rstd = rsqrtf(var + 1e-12f);
      #pragma unroll
      for (int k = 0; k < 3; ++k) {
        const float c = (v[n][k] - mu) * rstd * g[k] + be[k];
        S[k] += c; SS[k] += c * c;
      }
    }
    #pragma unroll
    for (int k = 0; k < 3; ++k) {
      const int h = t + k * 256;
      const float sl = sel_ln[(size_t)b * H + h];
      const float n1 = 2.8284271247461903f * fabsf(sl);  // sqrt(8)*|sel|
      const float n2 = sqrtf(SS[k]);
      out[(size_t)b * H + h] = sl * S[k] / (fmaxf(n1, 1e-8f) * fmaxf(n2, 1e-8f));
    }
    __syncthreads();
  }
}

// ---------------------------------------------------------------------------
extern "C" void kernel_launch(void* const* d_in, const int* in_sizes, int n_in,
                              void* d_out, int out_size, void* d_ws, size_t ws_size,
                              hipStream_t stream) {
  const float* hidden_states = (const float*)d_in[0];
  const float* sent_h1       = (const float*)d_in[1];
  const float* sent_h2       = (const float*)d_in[2];
  const int*   attention_mask= (const int*)  d_in[3];
  const float* expl_h1       = (const float*)d_in[4];
  const float* expl_h2       = (const float*)d_in[5];
  const int*   extra_am      = (const int*)  d_in[6];
  const int*   extra_index   = (const int*)  d_in[7];
  const int*   extra_start   = (const int*)  d_in[8];
  const int*   extra_end     = (const int*)  d_in[9];
  const float* W_attn        = (const float*)d_in[10];
  const float* W_t           = (const float*)d_in[11];
  const float* b_t           = (const float*)d_in[12];
  const float* gamma_t       = (const float*)d_in[13];
  const float* beta_t        = (const float*)d_in[14];
  const float* gamma_s       = (const float*)d_in[15];
  const float* beta_s        = (const float*)d_in[16];
  float* out = (float*)d_out;

  float* ws = (float*)d_ws;
  float* row_cls  = ws;                        // 512*768
  float* sp_part  = row_cls + 512 * H;         // 512*768
  float* sp_cnt   = sp_part + 512 * H;         // 512
  float* sel_part = sp_cnt + 512;              // 512*768
  float* sel_cnt  = sel_part + 512 * H;        // 512
  float* sel_ln   = sel_cnt + 512;             // 16*768
  float* sp       = sel_ln + B * H;            // 16*768
  float* simp     = sp + B * H;                // 16*12*32
  float* yb       = simp + B * 12 * S1;        // 128*768

  k_pool<<<1536, 384, 0, stream>>>(expl_h1, expl_h2, extra_am,
                                   sent_h1, sent_h2, attention_mask,
                                   hidden_states, extra_start, extra_end,
                                   row_cls, sp_part, sp_cnt, sel_part, sel_cnt);
  k_sp<<<32, 256, 0, stream>>>(sp_part, sp_cnt, sel_part, sel_cnt,
                               gamma_s, beta_s, sp, sel_ln);
  k_mid_q<<<192, 1024, 0, stream>>>(sp, W_attn, row_cls, simp);
  k_attn_tr<<<192, 1024, 0, stream>>>(simp, row_cls, extra_index, W_t, b_t, yb);
  k_lnscore<<<B, 256, 0, stream>>>(yb, gamma_t, beta_t, sel_ln, out);
}

// Round 13
// 73.445 us; speedup vs baseline: 10.2848x; 10.2848x over previous
//
#include <hip/hip_runtime.h>
#include <math.h>

// Problem constants (fixed by setup_inputs)
#define B   16
#define L   512
#define H   768
#define HV4 192      // H/4 float4s per row
#define S1  32
#define S2  128
#define NS  8
#define M   4
#define CH  16       // L-chunk rows per partial block
#define NCHUNK 32    // L / CH

// ---------------------------------------------------------------------------
// K1 (fused): 1536 blocks, 384 threads. [R7/R9/R11-validated, byte-identical]
// ---------------------------------------------------------------------------
__global__ __launch_bounds__(384)
void k_pool(const float* __restrict__ e1, const float* __restrict__ e2,
            const int* __restrict__ am,
            const float* __restrict__ s1, const float* __restrict__ s2,
            const int* __restrict__ iam,
            const float* __restrict__ hs, const int* __restrict__ st_,
            const int* __restrict__ en_,
            float* __restrict__ row_cls,
            float* __restrict__ sp_part, float* __restrict__ sp_cnt,
            float* __restrict__ sel_part, float* __restrict__ sel_cnt) {
  const int bid = blockIdx.x;
  const int t = threadIdx.x;
  const int half = t / 192;       // wave-uniform (waves 0-2 vs 3-5)
  const int tt = t % 192;
  __shared__ int   idxL[S2];
  __shared__ int   cntS;
  __shared__ float4 pf[192];      // half-1 partials for the combine

  if (bid < 512) {
    const int i = bid;
    if (t < 64) {
      const int m0 = am[i * S2 + t];
      const int m1 = am[i * S2 + 64 + t];
      const unsigned long long b0 = __ballot(m0 != 0);
      const unsigned long long b1 = __ballot(m1 != 0);
      const int c0 = (int)__popcll(b0);
      if (m0) idxL[(int)__popcll(b0 & ((1ULL << t) - 1))] = t;
      if (m1) idxL[c0 + (int)__popcll(b1 & ((1ULL << t) - 1))] = 64 + t;
      if (t == 0) cntS = c0 + (int)__popcll(b1);
    }
    __syncthreads();
    const int cnt = cntS;
    const int cntH = (cnt + 1 - half) >> 1;   // half0 ceil, half1 floor
    const float4* p1 = (const float4*)e1 + (size_t)i * (S2 * HV4) + tt;
    const float4* p2 = (const float4*)e2 + (size_t)i * (S2 * HV4) + tt;
    float ax = 0.f, ay = 0.f, az = 0.f, aw = 0.f;
    int kk = 0;
    for (; kk + 3 < cntH; kk += 4) {
      const int j0 = idxL[2 * kk + half];
      const int j1 = idxL[2 * (kk + 1) + half];
      const int j2 = idxL[2 * (kk + 2) + half];
      const int j3 = idxL[2 * (kk + 3) + half];
      float4 a0 = p1[j0 * HV4], b0 = p2[j0 * HV4];
      float4 a1 = p1[j1 * HV4], b1 = p2[j1 * HV4];
      float4 a2 = p1[j2 * HV4], b2 = p2[j2 * HV4];
      float4 a3 = p1[j3 * HV4], b3 = p2[j3 * HV4];
      ax += (a0.x + b0.x) + (a1.x + b1.x) + (a2.x + b2.x) + (a3.x + b3.x);
      ay += (a0.y + b0.y) + (a1.y + b1.y) + (a2.y + b2.y) + (a3.y + b3.y);
      az += (a0.z + b0.z) + (a1.z + b1.z) + (a2.z + b2.z) + (a3.z + b3.z);
      aw += (a0.w + b0.w) + (a1.w + b1.w) + (a2.w + b2.w) + (a3.w + b3.w);
    }
    for (; kk < cntH; ++kk) {
      const int j = idxL[2 * kk + half];
      float4 a = p1[j * HV4], b = p2[j * HV4];
      ax += a.x + b.x; ay += a.y + b.y; az += a.z + b.z; aw += a.w + b.w;
    }
    if (half == 1) { float4 o; o.x = ax; o.y = ay; o.z = az; o.w = aw; pf[tt] = o; }
    __syncthreads();
    if (half == 0) {
      const float inv = 1.f / (float)cnt;
      float4 o = pf[tt];
      o.x = (ax + o.x) * inv; o.y = (ay + o.y) * inv;
      o.z = (az + o.z) * inv; o.w = (aw + o.w) * inv;
      ((float4*)row_cls)[(size_t)i * HV4 + tt] = o;
    }
  } else if (bid < 1024) {
    const int blk = bid - 512;
    const int b = blk >> 5, c = blk & 31;
    if (t < 64) {
      const int m = (t < CH) ? iam[b * L + c * CH + t] : 0;
      const unsigned long long bm = __ballot(m != 0);
      if (m) idxL[(int)__popcll(bm & ((1ULL << t) - 1))] = t;
      if (t == 0) { const int cc = (int)__popcll(bm); cntS = cc; sp_cnt[blk] = (float)cc; }
    }
    __syncthreads();
    const int cnt = cntS;
    const int cntH = (cnt + 1 - half) >> 1;
    const float4* p1 = (const float4*)s1 + ((size_t)b * L + c * CH) * HV4 + tt;
    const float4* p2 = (const float4*)s2 + ((size_t)b * L + c * CH) * HV4 + tt;
    float ax = 0.f, ay = 0.f, az = 0.f, aw = 0.f;
    int kk = 0;
    for (; kk + 1 < cntH; kk += 2) {
      const int l0 = idxL[2 * kk + half];
      const int l1 = idxL[2 * (kk + 1) + half];
      float4 a0 = p1[l0 * HV4], b0 = p2[l0 * HV4];
      float4 a1 = p1[l1 * HV4], b1 = p2[l1 * HV4];
      ax += (a0.x + b0.x) + (a1.x + b1.x);
      ay += (a0.y + b0.y) + (a1.y + b1.y);
      az += (a0.z + b0.z) + (a1.z + b1.z);
      aw += (a0.w + b0.w) + (a1.w + b1.w);
    }
    for (; kk < cntH; ++kk) {
      const int l = idxL[2 * kk + half];
      float4 a = p1[l * HV4], b = p2[l * HV4];
      ax += a.x + b.x; ay += a.y + b.y; az += a.z + b.z; aw += a.w + b.w;
    }
    if (half == 1) { float4 o; o.x = ax; o.y = ay; o.z = az; o.w = aw; pf[tt] = o; }
    __syncthreads();
    if (half == 0) {
      float4 o = pf[tt];
      o.x += ax; o.y += ay; o.z += az; o.w += aw;
      ((float4*)sp_part)[(size_t)blk * HV4 + tt] = o;
    }
  } else {
    const int blk = bid - 1024;
    const int b = blk >> 5, c = blk & 31;
    const int st = st_[b], en = en_[b];
    const int lo = st > c * CH ? st : c * CH;
    const int hi = en < c * CH + CH ? en : c * CH + CH;
    const float4* p = (const float4*)hs + (size_t)b * L * HV4 + tt;
    float ax = 0.f, ay = 0.f, az = 0.f, aw = 0.f;
    for (int l = lo + half; l < hi; l += 2) {   // this half's rows, in-bounds
      float4 a0 = p[l * HV4];
      ax += a0.x; ay += a0.y; az += a0.z; aw += a0.w;
    }
    if (half == 1) { float4 o; o.x = ax; o.y = ay; o.z = az; o.w = aw; pf[tt] = o; }
    __syncthreads();
    if (half == 0) {
      float4 o = pf[tt];
      o.x += ax; o.y += ay; o.z += az; o.w += aw;
      ((float4*)sel_part)[(size_t)blk * HV4 + tt] = o;
      if (tt == 0) sel_cnt[blk] = (float)(hi > lo ? hi - lo : 0);
    }
  }
}

// ---------------------------------------------------------------------------
// K2: combines done ONCE. Grid 32 blocks, 256 threads. [R11-identical]
// ---------------------------------------------------------------------------
__global__ __launch_bounds__(256)
void k_sp(const float* __restrict__ sp_part, const float* __restrict__ sp_cnt,
          const float* __restrict__ sel_part, const float* __restrict__ sel_cnt,
          const float* __restrict__ gamma_s, const float* __restrict__ beta_s,
          float* __restrict__ sp, float* __restrict__ sel_ln) {
  const int bid = blockIdx.x, t = threadIdx.x;
  const int lane = t & 63, w = t >> 6;
  __shared__ float red[8];
  if (bid < B) {
    const int b = bid;
    float csp = 0.f;
    for (int c = 0; c < NCHUNK; ++c) csp += sp_cnt[b * NCHUNK + c];
    const float inv = 1.f / csp;
    #pragma unroll
    for (int k = 0; k < 3; ++k) {
      const int h = t + k * 256;
      float a = 0.f;
      #pragma unroll
      for (int c = 0; c < NCHUNK; ++c)
        a += sp_part[((size_t)b * NCHUNK + c) * H + h];
      sp[(size_t)b * H + h] = a * inv;
    }
  } else {
    const int b = bid - B;
    float csel = 0.f;
    for (int c = 0; c < NCHUNK; ++c) csel += sel_cnt[b * NCHUNK + c];
    const float invc = 1.f / csel;
    float selv[3];
    #pragma unroll
    for (int k = 0; k < 3; ++k) {
      const int h = t + k * 256;
      float s = 0.f;
      #pragma unroll
      for (int c = 0; c < NCHUNK; ++c)
        s += sel_part[((size_t)b * NCHUNK + c) * H + h];
      selv[k] = s * invc;
    }
    float s = selv[0] + selv[1] + selv[2];
    float ss = selv[0] * selv[0] + selv[1] * selv[1] + selv[2] * selv[2];
    #pragma unroll
    for (int off = 32; off > 0; off >>= 1) {
      s += __shfl_down(s, off);
      ss += __shfl_down(ss, off);
    }
    if (lane == 0) { red[w] = s; red[4 + w] = ss; }
    __syncthreads();
    const float S = red[0] + red[1] + red[2] + red[3];
    const float SS = red[4] + red[5] + red[6] + red[7];
    const float mu = S / (float)H;
    const float var = SS / (float)H - mu * mu;
    const float rstd = rsqrtf(var + 1e-12f);
    #pragma unroll
    for (int k = 0; k < 3; ++k) {
      const int h = t + k * 256;
      sel_ln[(size_t)b * H + h] = (selv[k] - mu) * rstd * gamma_s[h] + beta_s[h];
    }
  }
}

// ---------------------------------------------------------------------------
// K3: q-tile + sim partials, 1024 threads. [R11-identical — its W_attn walk
// is lane->h coalesced, measured small in R12]
// ---------------------------------------------------------------------------
__global__ __launch_bounds__(1024)
void k_mid_q(const float* __restrict__ sp, const float* __restrict__ W_attn,
             const float* __restrict__ rc, float* __restrict__ simp) {
  const int bid = blockIdx.x, t = threadIdx.x;
  const int b = bid / 12, ht = bid % 12;
  const int lane = t & 63, w = t >> 6;     // 16 waves
  __shared__ float spL[H];
  __shared__ float red[1024];
  __shared__ float qt[64];
  if (t < H) spL[t] = sp[(size_t)b * H + t];
  __syncthreads();
  {
    const int h = ht * 64 + lane;
    const float* wp = W_attn + (size_t)(w * 48) * H + h;
    const float* sv = spL + w * 48;
    float acc = 0.f;
    #pragma unroll 8
    for (int i = 0; i < 48; ++i) acc += sv[i] * wp[(size_t)i * H];
    red[t] = acc;
  }
  __syncthreads();
  if (t < 64) {
    float a = 0.f;
    #pragma unroll
    for (int ww = 0; ww < 16; ++ww) a += red[ww * 64 + t];
    qt[t] = a;
  }
  __syncthreads();
  {
    const int i = t >> 5, sub = t & 31;
    const float* rr = rc + (size_t)(b * S1 + i) * H + ht * 64 + sub * 2;
    float p = qt[sub * 2] * rr[0] + qt[sub * 2 + 1] * rr[1];
    p += __shfl_down(p, 16);
    p += __shfl_down(p, 8);
    p += __shfl_down(p, 4);
    p += __shfl_down(p, 2);
    p += __shfl_down(p, 1);
    if (sub == 0) simp[((size_t)b * 12 + ht) * S1 + i] = p;
  }
}

// ---------------------------------------------------------------------------
// K4: softmax + pooled + y-stripe GEMM, 1024 threads (16 waves).
// R13 FIX: y-GEMM now COALESCED — wave w owns rows h = hc*64 + w*4 + r;
// all 64 lanes cooperatively load W_t[h][:] as 3 coalesced float4
// (1KB/instruction instead of 64 scattered cache lines), dot against the
// 8 pooled rows from LDS, shuffle-reduce, lane 0 stores.
// ---------------------------------------------------------------------------
__global__ __launch_bounds__(1024)
void k_attn_tr(const float* __restrict__ simp, const float* __restrict__ rc,
               const int* __restrict__ extra_index,
               const float* __restrict__ W_t, const float* __restrict__ b_t,
               float* __restrict__ yb) {
  const int bid = blockIdx.x, t = threadIdx.x;
  const int b = bid / 12, hc = bid % 12;
  const int lane = t & 63, w = t >> 6;     // 16 waves
  __shared__ float pL[NS * H];   // 24 KiB pooled
  __shared__ float simR[S1];
  __shared__ float w2L[S1];
  if (t < S1) {
    float a = 0.f;
    for (int ht = 0; ht < 12; ++ht)
      a += simp[((size_t)b * 12 + ht) * S1 + t];
    simR[t] = a;
  }
  __syncthreads();
  if (t < NS) {
    const int vid = extra_index[b * NS + t];
    const float scale = 0.036084391824351615f;  // 1/sqrt(768)
    float x[M], mx = -1e30f;
    #pragma unroll
    for (int m = 0; m < M; ++m) {
      x[m] = (m < vid) ? simR[t * M + m] * scale : -1e30f;
      mx = fmaxf(mx, x[m]);
    }
    float s = 0.f, e[M];
    #pragma unroll
    for (int m = 0; m < M; ++m) { e[m] = expf(x[m] - mx); s += e[m]; }
    #pragma unroll
    for (int m = 0; m < M; ++m) w2L[t * M + m] = e[m] / s;
  }
  __syncthreads();
  // pooled: thread d (0..767) computes all 8 n's (coalesced rc reads)
  if (t < H) {
    const int d = t;
    #pragma unroll
    for (int n = 0; n < NS; ++n) {
      float p = 0.f;
      #pragma unroll
      for (int m = 0; m < M; ++m)
        p += w2L[n * M + m] * rc[(size_t)(b * S1 + n * M + m) * H + d];
      pL[n * H + d] = p;
    }
  }
  __syncthreads();
  // y GEMM (coalesced): wave w -> rows h = hc*64 + w*4 + r
  #pragma unroll 1
  for (int r = 0; r < 4; ++r) {
    const int h = hc * 64 + w * 4 + r;
    const float4* wr = (const float4*)(W_t + (size_t)h * H);
    const float4 wv0 = wr[lane];
    const float4 wv1 = wr[lane + 64];
    const float4 wv2 = wr[lane + 128];
    float part[NS];
    #pragma unroll
    for (int n = 0; n < NS; ++n) {
      const float4* pq = (const float4*)(pL + n * H);
      const float4 p0 = pq[lane];
      const float4 p1 = pq[lane + 64];
      const float4 p2 = pq[lane + 128];
      part[n] = wv0.x * p0.x + wv0.y * p0.y + wv0.z * p0.z + wv0.w * p0.w
              + wv1.x * p1.x + wv1.y * p1.y + wv1.z * p1.z + wv1.w * p1.w
              + wv2.x * p2.x + wv2.y * p2.y + wv2.z * p2.z + wv2.w * p2.w;
    }
    #pragma unroll
    for (int off = 32; off > 0; off >>= 1) {
      #pragma unroll
      for (int n = 0; n < NS; ++n) part[n] += __shfl_down(part[n], off);
    }
    if (lane == 0) {
      const float bias = b_t[h];
      #pragma unroll
      for (int n = 0; n < NS; ++n)
        yb[((size_t)b * NS + n) * H + h] = part[n] + bias;
    }
  }
}

// ---------------------------------------------------------------------------
// K5: fused row-LayerNorm + cosine score. [R7-validated, byte-identical]
// ---------------------------------------------------------------------------
__global__ __launch_bounds__(256)
void k_lnscore(const float* __restrict__ yb, const float* __restrict__ gamma,
               const float* __restrict__ beta, const float* __restrict__ sel_ln,
               float* __restrict__ out) {
  const int b = blockIdx.x, t = threadIdx.x;
  const int lane = t & 63, w = t >> 6;
  __shared__ float redS[NS * 4];
  __shared__ float redQ[NS * 4];
  float v[NS][3];
  for (int n = 0; n < NS; ++n) {
    float s = 0.f, ss = 0.f;
    #pragma unroll
    for (int k = 0; k < 3; ++k) {
      const float x = yb[((size_t)b * NS + n) * H + t + k * 256];
      v[n][k] = x; s += x; ss += x * x;
    }
    #pragma unroll
    for (int off = 32; off > 0; off >>= 1) {
      s += __shfl_down(s, off);
      ss += __shfl_down(ss, off);
    }
    if (lane == 0) { redS[n * 4 + w] = s; redQ[n * 4 + w] = ss; }
  }
  __syncthreads();
  float g[3], be[3];
  #pragma unroll
  for (int k = 0; k < 3; ++k) { g[k] = gamma[t + k * 256]; be[k] = beta[t + k * 256]; }
  float S[3] = {0.f, 0.f, 0.f}, SS[3] = {0.f, 0.f, 0.f};
  for (int n = 0; n < NS; ++n) {
    const float Sn = redS[n * 4] + redS[n * 4 + 1] + redS[n * 4 + 2] + redS[n * 4 + 3];
    const float Qn = redQ[n * 4] + redQ[n * 4 + 1] + redQ[n * 4 + 2] + redQ[n * 4 + 3];
    const float mu = Sn / (float)H;
    const float var = Qn / (float)H - mu * mu;
    const float rstd = rsqrtf(var + 1e-12f);
    #pragma unroll
    for (int k = 0; k < 3; ++k) {
      const float c = (v[n][k] - mu) * rstd * g[k] + be[k];
      S[k] += c; SS[k] += c * c;
    }
  }
  #pragma unroll
  for (int k = 0; k < 3; ++k) {
    const int h = t + k * 256;
    const float sl = sel_ln[(size_t)b * H + h];
    const float n1 = 2.8284271247461903f * fabsf(sl);  // sqrt(8)*|sel|
    const float n2 = sqrtf(SS[k]);
    out[(size_t)b * H + h] = sl * S[k] / (fmaxf(n1, 1e-8f) * fmaxf(n2, 1e-8f));
  }
}

// ---------------------------------------------------------------------------
extern "C" void kernel_launch(void* const* d_in, const int* in_sizes, int n_in,
                              void* d_out, int out_size, void* d_ws, size_t ws_size,
                              hipStream_t stream) {
  const float* hidden_states = (const float*)d_in[0];
  const float* sent_h1       = (const float*)d_in[1];
  const float* sent_h2       = (const float*)d_in[2];
  const int*   attention_mask= (const int*)  d_in[3];
  const float* expl_h1       = (const float*)d_in[4];
  const float* expl_h2       = (const float*)d_in[5];
  const int*   extra_am      = (const int*)  d_in[6];
  const int*   extra_index   = (const int*)  d_in[7];
  const int*   extra_start   = (const int*)  d_in[8];
  const int*   extra_end     = (const int*)  d_in[9];
  const float* W_attn        = (const float*)d_in[10];
  const float* W_t           = (const float*)d_in[11];
  const float* b_t           = (const float*)d_in[12];
  const float* gamma_t       = (const float*)d_in[13];
  const float* beta_t        = (const float*)d_in[14];
  const float* gamma_s       = (const float*)d_in[15];
  const float* beta_s        = (const float*)d_in[16];
  float* out = (float*)d_out;

  float* ws = (float*)d_ws;
  float* row_cls  = ws;                        // 512*768
  float* sp_part  = row_cls + 512 * H;         // 512*768
  float* sp_cnt   = sp_part + 512 * H;         // 512
  float* sel_part = sp_cnt + 512;              // 512*768
  float* sel_cnt  = sel_part + 512 * H;        // 512
  float* sel_ln   = sel_cnt + 512;             // 16*768
  float* sp       = sel_ln + B * H;            // 16*768
  float* simp     = sp + B * H;                // 16*12*32
  float* yb       = simp + B * 12 * S1;        // 128*768

  k_pool<<<1536, 384, 0, stream>>>(expl_h1, expl_h2, extra_am,
                                   sent_h1, sent_h2, attention_mask,
                                   hidden_states, extra_start, extra_end,
                                   row_cls, sp_part, sp_cnt, sel_part, sel_cnt);
  k_sp<<<32, 256, 0, stream>>>(sp_part, sp_cnt, sel_part, sel_cnt,
                               gamma_s, beta_s, sp, sel_ln);
  k_mid_q<<<192, 1024, 0, stream>>>(sp, W_attn, row_cls, simp);
  k_attn_tr<<<192, 1024, 0, stream>>>(simp, row_cls, extra_index, W_t, b_t, yb);
  k_lnscore<<<B, 256, 0, stream>>>(yb, gamma_t, beta_t, sel_ln, out);
}